// Round 7
// baseline (25.365 us; speedup 1.0000x reference)
//
#include <hip/hip_runtime.h>

// ResampleLayer: linear time-resampling of [B,S,D] f32 embeddings from sorted
// timestamps ts[B,S] onto a uniform grid of OUT_LEN points in [0, 100].
//
// B=32, S=4096, D=256, OUT_LEN=1001, t_l = l * 0.1.
//
// Two-kernel split so the payload waves spend ~100% of their life moving
// embed bytes:
//   K1 search_kernel: all 32x1001 lower_bound searches + lerp weights into
//      d_ws as (w, idx) pairs. ts rows are 16 KB, L1/L2-hot; ~1-2 us.
//   K2 payload_kernel: one wave per strip of 8 points. Loads its 8 (w,idx)
//      pairs (8-B broadcast loads, ONE dependency hop), then issues 16
//      independent 1-KB row loads into registers and 8 stores. No search on
//      the critical path.

#define RS_B 32
#define RS_S 4096
#define RS_D 256
#define RS_OUTLEN 1001
#define RS_PPW 8                         // points per wave (strip)
#define RS_NSTRIP 126                    // ceil(1001/8); last starts at 993
#define RS_WPB 4                         // waves per block (payload)
#define RS_NBLK (RS_B * RS_NSTRIP / RS_WPB)   // 1008 blocks (126*32/4)
#define RS_WSROW 1008                    // padded row stride in d_ws (pairs)

typedef float f32x4 __attribute__((ext_vector_type(4)));
typedef float f32x2 __attribute__((ext_vector_type(2)));

// ---- K1: per-lane binary search; writes (w, idx) per output point ----
__global__ __launch_bounds__(256) void search_kernel(
    const float* __restrict__ ts,      // [B, S] sorted
    f32x2* __restrict__ idxw)          // [B, RS_WSROW] (w, idx-as-float-bits)
{
    const int b = blockIdx.y;
    int l = blockIdx.x * 256 + threadIdx.x;    // 0..1023
    if (l > RS_OUTLEN - 1) l = RS_OUTLEN - 1;  // duplicate writes, same value

    const float t = (float)((double)l * (100.0 / 1000.0));
    const float* __restrict__ tsr = ts + (size_t)b * RS_S;

    int lo = 0, hi = RS_S;
#pragma unroll
    for (int it = 0; it < 12; ++it) {          // S = 2^12 -> 12 fixed steps
        int mid = (lo + hi) >> 1;
        if (tsr[mid] < t) lo = mid + 1; else hi = mid;
    }
    int idx = lo;
    if (idx < 1) idx = 1;
    if (idx > RS_S - 1) idx = RS_S - 1;

    const float x_lo = tsr[idx - 1];
    const float x_hi = tsr[idx];
    f32x2 p;
    p.x = (t - x_lo) / (x_hi - x_lo);
    p.y = __int_as_float(idx);
    idxw[(size_t)b * RS_WSROW + l] = p;
}

// ---- K2: pure gather/lerp/store payload ----
__global__ __launch_bounds__(256, 4) void payload_kernel(
    const float* __restrict__ embed,   // [B, S, D]
    const f32x2* __restrict__ idxw,    // [B, RS_WSROW]
    float* __restrict__ out)           // [B, OUT_LEN, D]
{
    // XCD-contiguous swizzle (1008 % 8 == 0 -> bijective).
    const int lin = blockIdx.x;                      // 0..1007
    const int bkid = (lin & 7) * (RS_NBLK / 8) + (lin >> 3);

    const int wave = threadIdx.x >> 6;
    const int lane = threadIdx.x & 63;

    const int sid = bkid * RS_WPB + wave;            // 0..4031
    const int b = sid / RS_NSTRIP;
    int l0 = (sid - b * RS_NSTRIP) * RS_PPW;
    if (l0 > RS_OUTLEN - RS_PPW) l0 = RS_OUTLEN - RS_PPW;  // 993 (overlap tail)

    // 8 broadcast pair loads — independent, one waitcnt.
    const f32x2* __restrict__ prow = idxw + (size_t)b * RS_WSROW + l0;
    f32x2 pw[RS_PPW];
#pragma unroll
    for (int q = 0; q < RS_PPW; ++q) pw[q] = prow[q];

    const f32x4* __restrict__ ebase =
        (const f32x4*)(embed + (size_t)b * RS_S * RS_D);   // row = 64 f32x4
    f32x4* __restrict__ obase =
        (f32x4*)(out + ((size_t)b * RS_OUTLEN + (size_t)l0) * RS_D);

    // 16 independent row loads in flight, then lerp + store.
    f32x4 va[RS_PPW], vc[RS_PPW];
#pragma unroll
    for (int q = 0; q < RS_PPW; ++q) {
        const int idx = __float_as_int(pw[q].y);
        const f32x4* plo = ebase + (size_t)(idx - 1) * (RS_D / 4) + lane;
        va[q] = __builtin_nontemporal_load(plo);
        vc[q] = __builtin_nontemporal_load(plo + (RS_D / 4));
    }
#pragma unroll
    for (int q = 0; q < RS_PPW; ++q) {
        f32x4 r = va[q] + (vc[q] - va[q]) * pw[q].x;
        __builtin_nontemporal_store(r, obase + (size_t)q * (RS_D / 4) + lane);
    }
}

extern "C" void kernel_launch(void* const* d_in, const int* in_sizes, int n_in,
                              void* d_out, int out_size, void* d_ws, size_t ws_size,
                              hipStream_t stream) {
    const float* embed = (const float*)d_in[0];  // [32, 4096, 256] f32
    const float* ts    = (const float*)d_in[1];  // [32, 4096] f32 sorted
    float* out         = (float*)d_out;          // [32, 1001, 256] f32
    f32x2* idxw        = (f32x2*)d_ws;           // 32*1008*8 B = 258 KB

    dim3 g1(4, RS_B);                            // 4*256 = 1024 >= 1001 points
    search_kernel<<<g1, 256, 0, stream>>>(ts, idxw);
    payload_kernel<<<RS_NBLK, RS_WPB * 64, 0, stream>>>(embed, idxw, out);
}

// Round 8
// 21.090 us; speedup vs baseline: 1.2027x; 1.2027x over previous
//
#include <hip/hip_runtime.h>

// ResampleLayer: linear time-resampling of [B,S,D] f32 embeddings from sorted
// timestamps ts[B,S] onto a uniform grid of OUT_LEN points in [0, 100].
//
// B=32, S=4096, D=256, OUT_LEN=1001, t_l = l * 0.1.
//
// FINAL STRUCTURE (round 6, best measured 21.09 us ~ 4.6 TB/s effective):
// 256-thread blocks (4 waves); each wave owns a strip of 8 consecutive
// output points. Search is a 2-round wave-parallel ballot scheme (2 parallel
// ts loads instead of a 12-deep dependent chain). Payload: all 16 row loads
// issued branch-free into registers (16 global_load_dwordx4 in flight per
// wave), then lerp + nt-store. Tail strip overlaps (starts at 993) so every
// strip is full — duplicate writes carry identical values (deterministic).
//
// Measured wall: ~75% of the 6.29 TB/s streaming ceiling on ~97 MB of
// traffic. Five independent levers (TLP, search depth, per-wave MLP, cache
// policy/swizzle, split-kernel search) all converge at 21-22.5 us — the
// limiter is DRAM-level efficiency of a 50%-dense 1-KB-row gather mixed
// with a write stream, which kernel structure cannot change.

#define RS_B 32
#define RS_S 4096
#define RS_D 256
#define RS_OUTLEN 1001
#define RS_PPW 8                         // points per wave (strip)
#define RS_NSTRIP 126                    // ceil(1001/8); last starts at 993
#define RS_WPB 4                         // waves per block
#define RS_NBX 32                        // ceil(126/4)

typedef float f32x4 __attribute__((ext_vector_type(4)));

__global__ __launch_bounds__(256, 4) void resample_kernel(
    const float* __restrict__ embed,   // [B, S, D]
    const float* __restrict__ ts,      // [B, S] sorted along S
    float* __restrict__ out)           // [B, OUT_LEN, D]
{
    // XCD-contiguous swizzle over the 1024-block grid (1024 % 8 == 0).
    const int lin = blockIdx.x;                    // 0..1023
    const int wg  = (lin & 7) * (RS_NBX * RS_B / 8) + (lin >> 3);
    const int b   = wg >> 5;                       // 0..31
    const int bx  = wg & 31;                       // 0..31

    const int wave = threadIdx.x >> 6;
    const int lane = threadIdx.x & 63;

    int sid = bx * RS_WPB + wave;                  // 0..127
    if (sid > RS_NSTRIP - 1) sid = RS_NSTRIP - 1;  // dup strips: identical writes
    int l0 = sid * RS_PPW;
    if (l0 > RS_OUTLEN - RS_PPW) l0 = RS_OUTLEN - RS_PPW;   // 993 (overlap)

    const float* __restrict__ tsr = ts + (size_t)b * RS_S;

    // ---- 2-round ballot search for all 8 points (results wave-uniform) ----
    // Round 1: lane i holds the LAST element of chunk i (64 chunks x 64).
    const float s1 = tsr[lane * 64 + 63];
    int cq[RS_PPW];
#pragma unroll
    for (int q = 0; q < RS_PPW; ++q) {
        const float tq = (float)((double)(l0 + q) * 0.1);
        cq[q] = __popcll(__ballot(s1 < tq));       // 0..64; ==64 -> idx = S
    }
    // Round 2: scan each point's chunk; lower_bound = c*64 + popcount.
    int idxq[RS_PPW];
#pragma unroll
    for (int q = 0; q < RS_PPW; ++q) {
        const float tq = (float)((double)(l0 + q) * 0.1);
        const int c = cq[q] < 63 ? cq[q] : 63;     // dummy chunk when cq==64
        const float w = tsr[c * 64 + lane];
        const int cnt = __popcll(__ballot(w < tq));
        int idx = (cq[q] >= 64) ? RS_S : c * 64 + cnt;
        if (idx < 1) idx = 1;
        if (idx > RS_S - 1) idx = RS_S - 1;
        idxq[q] = idx;
    }
    // Interpolation weights (same-address loads broadcast; ts row L1-hot).
    float swq[RS_PPW];
#pragma unroll
    for (int q = 0; q < RS_PPW; ++q) {
        const float tq = (float)((double)(l0 + q) * 0.1);
        const float x_lo = tsr[idxq[q] - 1];
        const float x_hi = tsr[idxq[q]];
        swq[q] = (tq - x_lo) / (x_hi - x_lo);
    }

    // ---- payload: 16 independent row loads, then lerp + store ----
    const f32x4* __restrict__ ebase =
        (const f32x4*)(embed + (size_t)b * RS_S * RS_D);    // row = 64 f32x4
    f32x4* __restrict__ obase =
        (f32x4*)(out + ((size_t)b * RS_OUTLEN + (size_t)l0) * RS_D);

    f32x4 va[RS_PPW], vc[RS_PPW];
#pragma unroll
    for (int q = 0; q < RS_PPW; ++q) {
        const f32x4* plo = ebase + (size_t)(idxq[q] - 1) * (RS_D / 4) + lane;
        va[q] = __builtin_nontemporal_load(plo);
        vc[q] = __builtin_nontemporal_load(plo + (RS_D / 4));
    }
#pragma unroll
    for (int q = 0; q < RS_PPW; ++q) {
        f32x4 r = va[q] + (vc[q] - va[q]) * swq[q];
        __builtin_nontemporal_store(r, obase + (size_t)q * (RS_D / 4) + lane);
    }
}

extern "C" void kernel_launch(void* const* d_in, const int* in_sizes, int n_in,
                              void* d_out, int out_size, void* d_ws, size_t ws_size,
                              hipStream_t stream) {
    const float* embed = (const float*)d_in[0];  // [32, 4096, 256] f32
    const float* ts    = (const float*)d_in[1];  // [32, 4096] f32 sorted
    float* out         = (float*)d_out;          // [32, 1001, 256] f32

    resample_kernel<<<RS_NBX * RS_B, RS_WPB * 64, 0, stream>>>(embed, ts, out);
}